// Round 1
// baseline (2725.365 us; speedup 1.0000x reference)
//
#include <hip/hip_runtime.h>
#include <cstddef>

// SelfAttn (SAGAN-style) on MI355X — Round 1: correct fp32 baseline.
// B=8 H=W=64 C=512 CK=64 CV=256; pooled keys P=1024.
// K1: theta = x @ w_theta                    [32768 x 64]
// K2: phi_p/g_p = maxpool2x2(x @ w_{phi,g})  [8192 x 64], [8192 x 256]
// K3: flash-style attention O = softmax(theta phi^T) g   [32768 x 256]
// K4: out = x + gamma * (O @ w_o)            [32768 x 512]

namespace {
constexpr int kB  = 8;
constexpr int kC  = 512;
constexpr int kCK = 64;
constexpr int kCV = 256;
constexpr int kHW = 4096;  // 64*64
constexpr int kW  = 64;    // image width
constexpr int kP  = 1024;  // pooled positions per batch (32*32)
}  // namespace

// ---------------- K1: theta = x @ w_theta ----------------
// M=32768, N=64, K=512. Tile 64x64, 256 thr, 4x4 micro, K-chunk 32.
__global__ __launch_bounds__(256) void k_theta(const float* __restrict__ x,
                                               const float* __restrict__ wt,
                                               float* __restrict__ theta) {
  __shared__ float As[64][33];
  __shared__ float Bs[32][65];
  const int tid = threadIdx.x;
  const int row0 = blockIdx.x * 64;
  const int ty = tid >> 4;  // 0..15
  const int tx = tid & 15;  // 0..15
  float acc[4][4] = {};
  for (int kc = 0; kc < kC; kc += 32) {
#pragma unroll
    for (int u = 0; u < 8; ++u) {
      int li = tid + u * 256;
      int r = li >> 5, k = li & 31;
      As[r][k] = x[(size_t)(row0 + r) * kC + kc + k];
    }
#pragma unroll
    for (int u = 0; u < 8; ++u) {
      int li = tid + u * 256;
      int k = li >> 6, n = li & 63;
      Bs[k][n] = wt[(size_t)(kc + k) * kCK + n];
    }
    __syncthreads();
#pragma unroll
    for (int kk = 0; kk < 32; ++kk) {
      float a[4], b[4];
#pragma unroll
      for (int i = 0; i < 4; ++i) a[i] = As[ty * 4 + i][kk];
#pragma unroll
      for (int j = 0; j < 4; ++j) b[j] = Bs[kk][tx * 4 + j];
#pragma unroll
      for (int i = 0; i < 4; ++i)
#pragma unroll
        for (int j = 0; j < 4; ++j) acc[i][j] += a[i] * b[j];
    }
    __syncthreads();
  }
#pragma unroll
  for (int i = 0; i < 4; ++i)
#pragma unroll
    for (int j = 0; j < 4; ++j)
      theta[(size_t)(row0 + ty * 4 + i) * kCK + tx * 4 + j] = acc[i][j];
}

// ---------------- K2: pooled projections phi_p [8192x64], g_p [8192x256] ----
// Each pooled output = max over 4 source-pixel dot products (pool AFTER conv).
// Tile: 32 pooled rows x 32 cols, 256 thr (8x32), 4 rows/thread x 4 src accs.
__global__ __launch_bounds__(256) void k_projpool(const float* __restrict__ x,
                                                  const float* __restrict__ wphi,
                                                  const float* __restrict__ wg,
                                                  float* __restrict__ phi_p,
                                                  float* __restrict__ g_p) {
  __shared__ float As[128][33];  // 32 pooled rows * 4 sources x 32 k
  __shared__ float Bs[32][33];
  const int tid = threadIdx.x;
  const int pr0 = blockIdx.x * 32;   // pooled row tile (0..8191)
  const int col0 = blockIdx.y * 32;  // 0..319 (0-63 phi, 64-319 g)
  const int ty = tid >> 5;           // 0..7
  const int tx = tid & 31;
  float acc[4][4] = {};  // [row i][source s]
  for (int kc = 0; kc < kC; kc += 32) {
#pragma unroll
    for (int u = 0; u < 16; ++u) {
      int li = tid + u * 256;  // 0..4095
      int sr = li >> 5, k = li & 31;
      int r = sr >> 2, s = sr & 3;
      int pp = pr0 + r;
      int b = pp >> 10;
      int pi = pp & 1023;
      int ph = pi >> 5, pw = pi & 31;
      int src = b * kHW + (2 * ph + (s >> 1)) * kW + 2 * pw + (s & 1);
      As[sr][k] = x[(size_t)src * kC + kc + k];
    }
#pragma unroll
    for (int u = 0; u < 4; ++u) {
      int li = tid + u * 256;  // 0..1023
      int k = li >> 5, n = li & 31;
      int col = col0 + n;
      Bs[k][n] = (col < kCK) ? wphi[(size_t)(kc + k) * kCK + col]
                             : wg[(size_t)(kc + k) * kCV + (col - kCK)];
    }
    __syncthreads();
#pragma unroll
    for (int kk = 0; kk < 32; ++kk) {
      float bv = Bs[kk][tx];
#pragma unroll
      for (int i = 0; i < 4; ++i)
#pragma unroll
        for (int s = 0; s < 4; ++s)
          acc[i][s] += As[(ty * 4 + i) * 4 + s][kk] * bv;
    }
    __syncthreads();
  }
#pragma unroll
  for (int i = 0; i < 4; ++i) {
    float m = fmaxf(fmaxf(acc[i][0], acc[i][1]), fmaxf(acc[i][2], acc[i][3]));
    int pp = pr0 + ty * 4 + i;
    if (col0 < kCK)
      phi_p[(size_t)pp * kCK + col0 + tx] = m;
    else
      g_p[(size_t)pp * kCV + (col0 - kCK) + tx] = m;
  }
}

// ---------------- K3: flash-style attention ----------------
// Per block: TQ=32 Q rows of one batch; iterate 16 key chunks of 64.
// Online softmax (m,l,alpha); O accumulated in registers (thread t owns V col t).
__global__ __launch_bounds__(256) void k_attn(const float* __restrict__ theta,
                                              const float* __restrict__ phi_p,
                                              const float* __restrict__ g_p,
                                              float* __restrict__ O) {
  constexpr int TQ = 32;
  constexpr int KC = 64;
  __shared__ float Qs[TQ][kCK + 1];
  __shared__ float Ps[KC][kCK + 1];
  __shared__ float E[TQ][KC + 1];
  __shared__ float red[TQ][8];
  __shared__ float mrow[TQ], lrow[TQ], alpha[TQ];

  const int tid = threadIdx.x;
  const int b = blockIdx.y;
  const int q0 = blockIdx.x * TQ;

#pragma unroll
  for (int u = 0; u < 8; ++u) {
    int li = tid + u * 256;
    int r = li >> 6, k = li & 63;
    Qs[r][k] = theta[((size_t)b * kHW + q0 + r) * kCK + k];
  }
  if (tid < TQ) {
    mrow[tid] = -1e30f;
    lrow[tid] = 0.f;
  }
  __syncthreads();

  float acc[TQ];
#pragma unroll
  for (int q = 0; q < TQ; ++q) acc[q] = 0.f;
  const int v = tid;        // V column owned by this thread
  const int qg = tid >> 6;  // 0..3 (score phase)
  const int pl = tid & 63;  // 0..63 (score phase)

  for (int c = 0; c < kP / KC; ++c) {
    // stage phi chunk 64x64
#pragma unroll
    for (int u = 0; u < 16; ++u) {
      int li = tid + u * 256;
      int r = li >> 6, k = li & 63;
      Ps[r][k] = phi_p[((size_t)b * kP + c * KC + r) * kCK + k];
    }
    __syncthreads();
    // scores: thread computes q = qg+4i (i<8) for key pl
    float sc[8];
#pragma unroll
    for (int i = 0; i < 8; ++i) sc[i] = 0.f;
#pragma unroll
    for (int kk = 0; kk < kCK; ++kk) {
      float pv = Ps[pl][kk];
#pragma unroll
      for (int i = 0; i < 8; ++i) sc[i] += Qs[qg + 4 * i][kk] * pv;
    }
#pragma unroll
    for (int i = 0; i < 8; ++i) E[qg + 4 * i][pl] = sc[i];
    __syncthreads();
    // chunk row max
    {
      int q = tid >> 3, sub = tid & 7;
      float m = E[q][sub];
#pragma unroll
      for (int j = 1; j < 8; ++j) m = fmaxf(m, E[q][sub + 8 * j]);
      red[q][sub] = m;
    }
    __syncthreads();
    if (tid < TQ) {
      float m = red[tid][0];
#pragma unroll
      for (int j = 1; j < 8; ++j) m = fmaxf(m, red[tid][j]);
      float mnew = fmaxf(mrow[tid], m);
      alpha[tid] = __expf(mrow[tid] - mnew);
      mrow[tid] = mnew;
    }
    __syncthreads();
    // exponentiate + partial row sums
    {
      int q = tid >> 3, sub = tid & 7;
      float mn = mrow[q];
      float s = 0.f;
#pragma unroll
      for (int j = 0; j < 8; ++j) {
        float e = __expf(E[q][sub + 8 * j] - mn);
        E[q][sub + 8 * j] = e;
        s += e;
      }
      red[q][sub] = s;
    }
    __syncthreads();
    if (tid < TQ) {
      float s = 0.f;
#pragma unroll
      for (int j = 0; j < 8; ++j) s += red[tid][j];
      lrow[tid] = lrow[tid] * alpha[tid] + s;
    }
    __syncthreads();
    // rescale + accumulate PV
#pragma unroll
    for (int q = 0; q < TQ; ++q) acc[q] *= alpha[q];
#pragma unroll 4
    for (int p = 0; p < KC; ++p) {
      float vv = g_p[((size_t)b * kP + c * KC + p) * kCV + v];
#pragma unroll
      for (int q = 0; q < TQ; ++q) acc[q] += E[q][p] * vv;
    }
    __syncthreads();  // E/Ps reused next chunk
  }
#pragma unroll
  for (int q = 0; q < TQ; ++q)
    O[((size_t)b * kHW + q0 + q) * kCV + v] = acc[q] / lrow[q];
}

// ---------------- K4: out = x + gamma * (O @ w_o) ----------------
// M=32768, K=256, N=512. Tile 64x64, 256 thr, 4x4 micro, K-chunk 32.
__global__ __launch_bounds__(256) void k_out(const float* __restrict__ Obuf,
                                             const float* __restrict__ wo,
                                             const float* __restrict__ x,
                                             const float* __restrict__ gamma,
                                             float* __restrict__ out) {
  __shared__ float As[64][33];
  __shared__ float Bs[32][65];
  const int tid = threadIdx.x;
  const int row0 = blockIdx.x * 64;
  const int col0 = blockIdx.y * 64;
  const int ty = tid >> 4, tx = tid & 15;
  float acc[4][4] = {};
  for (int kc = 0; kc < kCV; kc += 32) {
#pragma unroll
    for (int u = 0; u < 8; ++u) {
      int li = tid + u * 256;
      int r = li >> 5, k = li & 31;
      As[r][k] = Obuf[(size_t)(row0 + r) * kCV + kc + k];
    }
#pragma unroll
    for (int u = 0; u < 8; ++u) {
      int li = tid + u * 256;
      int k = li >> 6, n = li & 63;
      Bs[k][n] = wo[(size_t)(kc + k) * kC + col0 + n];
    }
    __syncthreads();
#pragma unroll
    for (int kk = 0; kk < 32; ++kk) {
      float a[4], bb[4];
#pragma unroll
      for (int i = 0; i < 4; ++i) a[i] = As[ty * 4 + i][kk];
#pragma unroll
      for (int j = 0; j < 4; ++j) bb[j] = Bs[kk][tx * 4 + j];
#pragma unroll
      for (int i = 0; i < 4; ++i)
#pragma unroll
        for (int j = 0; j < 4; ++j) acc[i][j] += a[i] * bb[j];
    }
    __syncthreads();
  }
  const float g = gamma[0];
#pragma unroll
  for (int i = 0; i < 4; ++i)
#pragma unroll
    for (int j = 0; j < 4; ++j) {
      size_t idx = (size_t)(row0 + ty * 4 + i) * kC + col0 + tx * 4 + j;
      out[idx] = x[idx] + g * acc[i][j];
    }
}

extern "C" void kernel_launch(void* const* d_in, const int* in_sizes, int n_in,
                              void* d_out, int out_size, void* d_ws, size_t ws_size,
                              hipStream_t stream) {
  (void)in_sizes; (void)n_in; (void)out_size; (void)ws_size;
  const float* x     = (const float*)d_in[0];
  const float* wt    = (const float*)d_in[1];
  const float* wphi  = (const float*)d_in[2];
  const float* wg    = (const float*)d_in[3];
  const float* wo    = (const float*)d_in[4];
  const float* gamma = (const float*)d_in[5];
  float* out = (float*)d_out;

  float* ws    = (float*)d_ws;
  float* theta = ws;                                  // 8*4096*64  = 2,097,152 f
  float* phi_p = theta + (size_t)kB * kHW * kCK;      // 8*1024*64  =   524,288 f
  float* g_p   = phi_p + (size_t)kB * kP * kCK;       // 8*1024*256 = 2,097,152 f
  float* Obuf  = g_p + (size_t)kB * kP * kCV;         // 8*4096*256 = 8,388,608 f
  // total workspace: 13,107,200 floats = 52.4 MB

  hipLaunchKernelGGL(k_theta, dim3(kB * kHW / 64), dim3(256), 0, stream, x, wt, theta);
  hipLaunchKernelGGL(k_projpool, dim3(kB * kP / 32, 10), dim3(256), 0, stream,
                     x, wphi, wg, phi_p, g_p);
  hipLaunchKernelGGL(k_attn, dim3(kHW / 32, kB), dim3(256), 0, stream,
                     theta, phi_p, g_p, Obuf);
  hipLaunchKernelGGL(k_out, dim3(kB * kHW / 64, kC / 64), dim3(256), 0, stream,
                     Obuf, wo, x, gamma, out);
}

// Round 2
// 265.034 us; speedup vs baseline: 10.2831x; 10.2831x over previous
//
#include <hip/hip_runtime.h>
#include <hip/hip_bf16.h>
#include <cstddef>
#include <cstdint>

// SelfAttn (SAGAN) — Round 2: bf16 MFMA pipeline.
// cast/pack -> theta GEMM -> phi/g GEMM -> pool -> S GEMM -> softmax -> PV GEMM -> out GEMM(+resid)

typedef __attribute__((ext_vector_type(8))) short short8;
typedef __attribute__((ext_vector_type(4))) float float4v;

namespace {
constexpr int kB = 8, kC = 512, kCK = 64, kCV = 256, kHW = 4096, kP = 1024;
}

__device__ __forceinline__ float b2f(short s) {
  unsigned u = ((unsigned)(unsigned short)s) << 16;
  float f;
  __builtin_memcpy(&f, &u, 4);
  return f;
}
__device__ __forceinline__ short f2b(float f) {
  __hip_bfloat16 h = __float2bfloat16(f);
  return __builtin_bit_cast(short, h);
}

// async global->LDS, 16B per lane; LDS dest = wave-uniform base + lane*16
__device__ __forceinline__ void gll16(const void* g, void* l) {
  __builtin_amdgcn_global_load_lds((uint32_t __attribute__((address_space(1)))*)g,
                                   (uint32_t __attribute__((address_space(3)))*)l,
                                   16, 0, 0);
}

template <typename T>
__device__ __forceinline__ float4v mfma16(T a, T b, float4v c) {
  return __builtin_amdgcn_mfma_f32_16x16x32_bf16(a, b, c, 0, 0, 0);
}

enum { EPI_BF16 = 0, EPI_RESID = 2 };

// C[m][n] = sum_k A[m][k] * B[n][k]   (B is N x K, i.e. B^T input)
// BM x BN tile, 256 thr = 4 waves arranged WR x WC, 16x16x32 bf16 MFMA.
template <int BM, int BN, int WR, int WC, int EPI>
__global__ __launch_bounds__(256) void gemm_bt(
    const __hip_bfloat16* __restrict__ A, const __hip_bfloat16* __restrict__ B,
    void* __restrict__ C, int M, int N, int K,
    long sAb, long sBb, long sCb,
    const float* __restrict__ xres, const float* __restrict__ gamma) {
  constexpr int TM = BM / WR, TN = BN / WC;
  constexpr int NMT = TM / 16, NNT = TN / 16;
  __shared__ __hip_bfloat16 As[BM * 64];
  __shared__ __hip_bfloat16 Bs[BN * 64];
  const int tid = threadIdx.x;
  const int wid = tid >> 6;
  const int lane = tid & 63;
  const int m = lane & 15, quad = lane >> 4;
  const int row0 = blockIdx.x * BM;
  const int col0 = blockIdx.y * BN;
  const int wm = (wid / WC) * TM;
  const int wn = (wid % WC) * TN;
  const __hip_bfloat16* Ab = A + (size_t)blockIdx.z * sAb;
  const __hip_bfloat16* Bb = B + (size_t)blockIdx.z * sBb;

  float4v acc[NMT][NNT] = {};

  const int srow = tid >> 3;        // 0..31
  const int scol = (tid & 7) * 8;   // 0..56
  const __hip_bfloat16* aptr = Ab + (size_t)(row0 + srow) * K + scol;
  const __hip_bfloat16* bptr = Bb + (size_t)(col0 + srow) * K + scol;

  for (int kc = 0; kc < K; kc += 64) {
#pragma unroll
    for (int u = 0; u < BM / 32; ++u)
      gll16(aptr + (size_t)u * 32 * K + kc, &As[(u * 32 + wid * 8) * 64]);
#pragma unroll
    for (int u = 0; u < BN / 32; ++u)
      gll16(bptr + (size_t)u * 32 * K + kc, &Bs[(u * 32 + wid * 8) * 64]);
    __syncthreads();
#pragma unroll
    for (int kk = 0; kk < 64; kk += 32) {
      short8 af[NMT], bfr[NNT];
#pragma unroll
      for (int i = 0; i < NMT; ++i)
        af[i] = *(const short8*)&As[(wm + i * 16 + m) * 64 + kk + quad * 8];
#pragma unroll
      for (int j = 0; j < NNT; ++j)
        bfr[j] = *(const short8*)&Bs[(wn + j * 16 + m) * 64 + kk + quad * 8];
#pragma unroll
      for (int i = 0; i < NMT; ++i)
#pragma unroll
        for (int j = 0; j < NNT; ++j)
          acc[i][j] = mfma16(af[i], bfr[j], acc[i][j]);
    }
    __syncthreads();
  }
  // epilogue: C/D layout col=lane&15, row=quad*4+r
#pragma unroll
  for (int i = 0; i < NMT; ++i) {
#pragma unroll
    for (int j = 0; j < NNT; ++j) {
      const int cc = col0 + wn + j * 16 + m;
      const int rb = row0 + wm + i * 16 + quad * 4;
#pragma unroll
      for (int r = 0; r < 4; ++r) {
        const size_t idx = (size_t)blockIdx.z * sCb + (size_t)(rb + r) * N + cc;
        if constexpr (EPI == EPI_BF16) {
          ((__hip_bfloat16*)C)[idx] = __float2bfloat16(acc[i][j][r]);
        } else {
          ((float*)C)[idx] = xres[idx] + gamma[0] * acc[i][j][r];
        }
      }
    }
  }
}

// x fp32 -> bf16, 8 elems/thread
__global__ __launch_bounds__(256) void k_cast_x(const float* __restrict__ x,
                                                __hip_bfloat16* __restrict__ xb) {
  const int i = blockIdx.x * 256 + threadIdx.x;
  const float4v* xv = (const float4v*)x;
  float4v v0 = xv[i * 2], v1 = xv[i * 2 + 1];
  short8 o;
  o[0] = f2b(v0[0]); o[1] = f2b(v0[1]); o[2] = f2b(v0[2]); o[3] = f2b(v0[3]);
  o[4] = f2b(v1[0]); o[5] = f2b(v1[1]); o[6] = f2b(v1[2]); o[7] = f2b(v1[3]);
  ((short8*)xb)[i] = o;
}

// transpose+cast weights: wtT[64][512], wpgT[320][512] (phi rows 0-63, g rows 64-319), woT[512][256]
__global__ __launch_bounds__(256) void k_pack_w(
    const float* __restrict__ wt, const float* __restrict__ wphi,
    const float* __restrict__ wg, const float* __restrict__ wo,
    __hip_bfloat16* __restrict__ wtT, __hip_bfloat16* __restrict__ wpgT,
    __hip_bfloat16* __restrict__ woT) {
  int idx = blockIdx.x * 256 + threadIdx.x;
  if (idx < 32768) {
    int n = idx >> 9, k = idx & 511;
    wtT[idx] = __float2bfloat16(wt[k * 64 + n]);
  } else if (idx < 32768 + 163840) {
    int t = idx - 32768;
    int n = t >> 9, k = t & 511;
    float v = (n < 64) ? wphi[k * 64 + n] : wg[k * 256 + (n - 64)];
    wpgT[t] = __float2bfloat16(v);
  } else {
    int t = idx - 196608;
    int n = t >> 8, k = t & 255;
    woT[t] = __float2bfloat16(wo[k * 512 + n]);
  }
}

// phi_p[b][p][c] = max over 2x2 of pg_full[b][h][w][c], c<64
__global__ __launch_bounds__(256) void k_pool_phi(const __hip_bfloat16* __restrict__ pg,
                                                  __hip_bfloat16* __restrict__ phi_p) {
  int idx = blockIdx.x * 256 + threadIdx.x;  // 524288
  int c = idx & 63;
  int p = (idx >> 6) & 1023;
  int b = idx >> 16;
  int ph = p >> 5, pw = p & 31;
  size_t base = ((size_t)b * 4096 + ph * 128 + pw * 2) * 320 + c;
  float v0 = __bfloat162float(pg[base]);
  float v1 = __bfloat162float(pg[base + 320]);
  float v2 = __bfloat162float(pg[base + 320 * 64]);
  float v3 = __bfloat162float(pg[base + 320 * 64 + 320]);
  phi_p[idx] = __float2bfloat16(fmaxf(fmaxf(v0, v1), fmaxf(v2, v3)));
}

// gT[b][v][p] = max over 2x2 of pg_full[b][h][w][64+v]  (LDS transpose for coalesced IO)
__global__ __launch_bounds__(256) void k_pool_gT(const __hip_bfloat16* __restrict__ pg,
                                                 __hip_bfloat16* __restrict__ gT) {
  __shared__ __hip_bfloat16 t[64][65];
  const int p0 = blockIdx.x * 64, v0 = blockIdx.y * 64, b = blockIdx.z;
#pragma unroll
  for (int it = 0; it < 16; ++it) {
    int li = it * 256 + threadIdx.x;
    int pp = li >> 6, v = li & 63;
    int p = p0 + pp;
    int ph = p >> 5, pw = p & 31;
    size_t base = ((size_t)b * 4096 + ph * 128 + pw * 2) * 320 + 64 + v0 + v;
    float m = fmaxf(
        fmaxf(__bfloat162float(pg[base]), __bfloat162float(pg[base + 320])),
        fmaxf(__bfloat162float(pg[base + 320 * 64]), __bfloat162float(pg[base + 320 * 64 + 320])));
    t[pp][v] = __float2bfloat16(m);
  }
  __syncthreads();
#pragma unroll
  for (int it = 0; it < 16; ++it) {
    int li = it * 256 + threadIdx.x;
    int v = li >> 6, p = li & 63;
    gT[((size_t)b * 256 + v0 + v) * 1024 + p0 + p] = t[p][v];
  }
}

// in-place row softmax over 1024 cols, bf16 storage, fp32 math; 1 wave per row
__global__ __launch_bounds__(256) void k_softmax(__hip_bfloat16* __restrict__ S) {
  const int row = blockIdx.x * 4 + (threadIdx.x >> 6);
  const int lane = threadIdx.x & 63;
  __hip_bfloat16* p = S + (size_t)row * 1024 + lane * 16;
  short8 a = *(short8*)p;
  short8 b = *(short8*)(p + 8);
  float v[16];
#pragma unroll
  for (int i = 0; i < 8; ++i) { v[i] = b2f(a[i]); v[8 + i] = b2f(b[i]); }
  float mx = v[0];
#pragma unroll
  for (int i = 1; i < 16; ++i) mx = fmaxf(mx, v[i]);
#pragma unroll
  for (int d = 1; d < 64; d <<= 1) mx = fmaxf(mx, __shfl_xor(mx, d));
  float s = 0.f;
#pragma unroll
  for (int i = 0; i < 16; ++i) { v[i] = __expf(v[i] - mx); s += v[i]; }
#pragma unroll
  for (int d = 1; d < 64; d <<= 1) s += __shfl_xor(s, d);
  const float inv = 1.f / s;
  short8 oa, ob;
#pragma unroll
  for (int i = 0; i < 8; ++i) { oa[i] = f2b(v[i] * inv); ob[i] = f2b(v[8 + i] * inv); }
  *(short8*)p = oa;
  *(short8*)(p + 8) = ob;
}

extern "C" void kernel_launch(void* const* d_in, const int* in_sizes, int n_in,
                              void* d_out, int out_size, void* d_ws, size_t ws_size,
                              hipStream_t stream) {
  (void)in_sizes; (void)n_in; (void)out_size; (void)ws_size;
  const float* x     = (const float*)d_in[0];
  const float* wt    = (const float*)d_in[1];
  const float* wphi  = (const float*)d_in[2];
  const float* wg    = (const float*)d_in[3];
  const float* wo    = (const float*)d_in[4];
  const float* gamma = (const float*)d_in[5];
  float* out = (float*)d_out;

  // workspace layout (bytes); xbf aliases O (xbf dead after pg GEMM),
  // pg_full aliases S (pg_full dead after pool kernels). total 110.8 MB.
  char* ws = (char*)d_ws;
  __hip_bfloat16* xbf   = (__hip_bfloat16*)(ws);              // 33,554,432
  __hip_bfloat16* wtT   = (__hip_bfloat16*)(ws + 33554432);   //     65,536
  __hip_bfloat16* wpgT  = (__hip_bfloat16*)(ws + 33619968);   //    327,680
  __hip_bfloat16* woT   = (__hip_bfloat16*)(ws + 33947648);   //    262,144
  __hip_bfloat16* theta = (__hip_bfloat16*)(ws + 34209792);   //  4,194,304
  __hip_bfloat16* phip  = (__hip_bfloat16*)(ws + 38404096);   //  1,048,576
  __hip_bfloat16* gT    = (__hip_bfloat16*)(ws + 39452672);   //  4,194,304
  __hip_bfloat16* S     = (__hip_bfloat16*)(ws + 43646976);   // 67,108,864
  __hip_bfloat16* pgf   = S;                                  // 20,971,520 (sub-span)
  __hip_bfloat16* O     = xbf;                                // 16,777,216 (sub-span)

  k_cast_x<<<8192, 256, 0, stream>>>(x, xbf);
  k_pack_w<<<1280, 256, 0, stream>>>(wt, wphi, wg, wo, wtT, wpgT, woT);
  // theta = x @ w_theta : [32768 x 64]
  gemm_bt<128, 64, 4, 1, EPI_BF16><<<dim3(256, 1, 1), 256, 0, stream>>>(
      xbf, wtT, theta, 32768, 64, 512, 0, 0, 0, nullptr, nullptr);
  // pg_full = x @ [w_phi|w_g] : [32768 x 320]
  gemm_bt<128, 64, 4, 1, EPI_BF16><<<dim3(256, 5, 1), 256, 0, stream>>>(
      xbf, wpgT, pgf, 32768, 320, 512, 0, 0, 0, nullptr, nullptr);
  k_pool_phi<<<2048, 256, 0, stream>>>(pgf, phip);
  k_pool_gT<<<dim3(16, 4, 8), 256, 0, stream>>>(pgf, gT);
  // S = theta @ phi_p^T : batched [8][4096 x 1024]
  gemm_bt<128, 128, 2, 2, EPI_BF16><<<dim3(32, 8, 8), 256, 0, stream>>>(
      theta, phip, S, 4096, 1024, 64, 262144, 65536, 4194304, nullptr, nullptr);
  k_softmax<<<8192, 256, 0, stream>>>(S);
  // O = P @ g : batched [8][4096 x 256]
  gemm_bt<128, 128, 2, 2, EPI_BF16><<<dim3(32, 2, 8), 256, 0, stream>>>(
      S, gT, O, 4096, 256, 1024, 4194304, 262144, 1048576, nullptr, nullptr);
  // out = x + gamma * (O @ w_o) : [32768 x 512]
  gemm_bt<128, 128, 2, 2, EPI_RESID><<<dim3(256, 4, 1), 256, 0, stream>>>(
      O, woT, out, 32768, 512, 256, 0, 0, 0, x, gamma);
}

// Round 3
// 263.117 us; speedup vs baseline: 10.3580x; 1.0073x over previous
//
#include <hip/hip_runtime.h>
#include <hip/hip_bf16.h>
#include <cstddef>
#include <cstdint>

// SelfAttn (SAGAN) — Round 3: fused flash-style MFMA attention + merged projection.
// cast -> pack -> proj GEMM [32768x384] -> pools -> fused attn (QK^T+softmax+PV) -> out GEMM(+resid)

typedef __attribute__((ext_vector_type(8))) short short8;
typedef __attribute__((ext_vector_type(4))) float float4v;

namespace {
constexpr int kB = 8, kC = 512, kCK = 64, kCV = 256, kHW = 4096, kP = 1024;
constexpr int kNP = 384;  // packed projection width: [theta|phi|g]
}

__device__ __forceinline__ short f2b(float f) {
  __hip_bfloat16 h = __float2bfloat16(f);
  return __builtin_bit_cast(short, h);
}

// async global->LDS, 16B/lane; LDS dest = wave-uniform base + lane*16
__device__ __forceinline__ void gll16(const void* g, void* l) {
  __builtin_amdgcn_global_load_lds((uint32_t __attribute__((address_space(1)))*)g,
                                   (uint32_t __attribute__((address_space(3)))*)l,
                                   16, 0, 0);
}

__device__ __forceinline__ float4v mfma16(short8 a, short8 b, float4v c) {
  return __builtin_amdgcn_mfma_f32_16x16x32_bf16(a, b, c, 0, 0, 0);
}

enum { EPI_BF16 = 0, EPI_RESID = 2 };

// C[m][n] = sum_k A[m][k] * B[n][k]  (B is NxK). BMxBN tile, 256 thr, 4 waves WRxWC.
template <int BM, int BN, int WR, int WC, int EPI>
__global__ __launch_bounds__(256) void gemm_bt(
    const __hip_bfloat16* __restrict__ A, const __hip_bfloat16* __restrict__ B,
    void* __restrict__ C, int M, int N, int K,
    const float* __restrict__ xres, const float* __restrict__ gamma) {
  constexpr int TM = BM / WR, TN = BN / WC;
  constexpr int NMT = TM / 16, NNT = TN / 16;
  __shared__ __hip_bfloat16 As[BM * 64];
  __shared__ __hip_bfloat16 Bs[BN * 64];
  const int tid = threadIdx.x;
  const int wid = tid >> 6;
  const int lane = tid & 63;
  const int m = lane & 15, quad = lane >> 4;
  const int row0 = blockIdx.x * BM;
  const int col0 = blockIdx.y * BN;
  const int wm = (wid / WC) * TM;
  const int wn = (wid % WC) * TN;

  float4v acc[NMT][NNT] = {};

  const int srow = tid >> 3;       // 0..31
  const int scol = (tid & 7) * 8;  // 0..56
  const __hip_bfloat16* aptr = A + (size_t)(row0 + srow) * K + scol;
  const __hip_bfloat16* bptr = B + (size_t)(col0 + srow) * K + scol;

  for (int kc = 0; kc < K; kc += 64) {
#pragma unroll
    for (int u = 0; u < BM / 32; ++u)
      gll16(aptr + (size_t)u * 32 * K + kc, &As[(u * 32 + wid * 8) * 64]);
#pragma unroll
    for (int u = 0; u < BN / 32; ++u)
      gll16(bptr + (size_t)u * 32 * K + kc, &Bs[(u * 32 + wid * 8) * 64]);
    __syncthreads();
#pragma unroll
    for (int kk = 0; kk < 64; kk += 32) {
      short8 af[NMT], bfr[NNT];
#pragma unroll
      for (int i = 0; i < NMT; ++i)
        af[i] = *(const short8*)&As[(wm + i * 16 + m) * 64 + kk + quad * 8];
#pragma unroll
      for (int j = 0; j < NNT; ++j)
        bfr[j] = *(const short8*)&Bs[(wn + j * 16 + m) * 64 + kk + quad * 8];
#pragma unroll
      for (int i = 0; i < NMT; ++i)
#pragma unroll
        for (int j = 0; j < NNT; ++j)
          acc[i][j] = mfma16(af[i], bfr[j], acc[i][j]);
    }
    __syncthreads();
  }
#pragma unroll
  for (int i = 0; i < NMT; ++i) {
#pragma unroll
    for (int j = 0; j < NNT; ++j) {
      const int cc = col0 + wn + j * 16 + m;
      const int rb = row0 + wm + i * 16 + quad * 4;
#pragma unroll
      for (int r = 0; r < 4; ++r) {
        const size_t idx = (size_t)(rb + r) * N + cc;
        if constexpr (EPI == EPI_BF16) {
          ((__hip_bfloat16*)C)[idx] = __float2bfloat16(acc[i][j][r]);
        } else {
          ((float*)C)[idx] = xres[idx] + gamma[0] * acc[i][j][r];
        }
      }
    }
  }
}

// x fp32 -> bf16, 8 elems/thread
__global__ __launch_bounds__(256) void k_cast_x(const float* __restrict__ x,
                                                __hip_bfloat16* __restrict__ xb) {
  const int i = blockIdx.x * 256 + threadIdx.x;
  const float4v* xv = (const float4v*)x;
  float4v v0 = xv[i * 2], v1 = xv[i * 2 + 1];
  short8 o;
  o[0] = f2b(v0[0]); o[1] = f2b(v0[1]); o[2] = f2b(v0[2]); o[3] = f2b(v0[3]);
  o[4] = f2b(v1[0]); o[5] = f2b(v1[1]); o[6] = f2b(v1[2]); o[7] = f2b(v1[3]);
  ((short8*)xb)[i] = o;
}

// pack weights: wAll[384][512] = [theta|phi|g]^T rows; woT[512][256]
__global__ __launch_bounds__(256) void k_pack_w(
    const float* __restrict__ wt, const float* __restrict__ wphi,
    const float* __restrict__ wg, const float* __restrict__ wo,
    __hip_bfloat16* __restrict__ wAll, __hip_bfloat16* __restrict__ woT) {
  int idx = blockIdx.x * 256 + threadIdx.x;  // 327680 total
  if (idx < 196608) {
    int n = idx >> 9, k = idx & 511;
    float v = (n < 64) ? wt[k * 64 + n]
            : (n < 128) ? wphi[k * 64 + (n - 64)]
                        : wg[k * 256 + (n - 128)];
    wAll[idx] = __float2bfloat16(v);
  } else {
    int t = idx - 196608;
    int n = t >> 8, k = t & 255;
    woT[t] = __float2bfloat16(wo[k * 512 + n]);
  }
}

// phi_p[b][p][c] = max 2x2 of pgf[b,h,w,64+c]
__global__ __launch_bounds__(256) void k_pool_phi(const __hip_bfloat16* __restrict__ pg,
                                                  __hip_bfloat16* __restrict__ phi_p) {
  int idx = blockIdx.x * 256 + threadIdx.x;  // 524288
  int c = idx & 63;
  int p = (idx >> 6) & 1023;
  int b = idx >> 16;
  int ph = p >> 5, pw = p & 31;
  size_t base = ((size_t)b * 4096 + ph * 128 + pw * 2) * kNP + 64 + c;
  float v0 = __bfloat162float(pg[base]);
  float v1 = __bfloat162float(pg[base + kNP]);
  float v2 = __bfloat162float(pg[base + kNP * 64]);
  float v3 = __bfloat162float(pg[base + kNP * 64 + kNP]);
  phi_p[idx] = __float2bfloat16(fmaxf(fmaxf(v0, v1), fmaxf(v2, v3)));
}

// gT[b][v][p] = max 2x2 of pgf[b,h,w,128+v]  (transposed for B^T operand)
__global__ __launch_bounds__(256) void k_pool_gT(const __hip_bfloat16* __restrict__ pg,
                                                 __hip_bfloat16* __restrict__ gT) {
  __shared__ __hip_bfloat16 t[64][65];
  const int p0 = blockIdx.x * 64, v0 = blockIdx.y * 64, b = blockIdx.z;
#pragma unroll
  for (int it = 0; it < 16; ++it) {
    int li = it * 256 + threadIdx.x;
    int pp = li >> 6, v = li & 63;
    int p = p0 + pp;
    int ph = p >> 5, pw = p & 31;
    size_t base = ((size_t)b * 4096 + ph * 128 + pw * 2) * kNP + 128 + v0 + v;
    float m = fmaxf(
        fmaxf(__bfloat162float(pg[base]), __bfloat162float(pg[base + kNP])),
        fmaxf(__bfloat162float(pg[base + kNP * 64]), __bfloat162float(pg[base + kNP * 64 + kNP])));
    t[pp][v] = __float2bfloat16(m);
  }
  __syncthreads();
#pragma unroll
  for (int it = 0; it < 16; ++it) {
    int li = it * 256 + threadIdx.x;
    int v = li >> 6, p = li & 63;
    gT[((size_t)b * 256 + v0 + v) * 1024 + p0 + p] = t[p][v];
  }
}

// -------- fused attention: O = softmax(theta phi^T) g, one block = 32 Q rows --------
// 512 thr = 8 waves. Phase1: scores sc[2][8] (waves split 1024 keys, chunk=256 staged).
// Phase2: exact softmax in regs (quad shuffle + cross-wave LDS reduce); P unnormalized.
// Phase3: per 128-key chunk: P->LDS (pad 136), g chunk [256][128] async, PV MFMA; scale at store.
__global__ __launch_bounds__(512) void k_fattn(
    const __hip_bfloat16* __restrict__ pgf,   // [B*4096][384]; theta = cols 0..63
    const __hip_bfloat16* __restrict__ phip,  // [B][1024][64]
    const __hip_bfloat16* __restrict__ gT,    // [B][256][1024]
    __hip_bfloat16* __restrict__ O) {         // [B][4096][256]
  __shared__ __align__(16) char smem[65536 + 8704 + 1024 + 128];
  __hip_bfloat16* Ks = (__hip_bfloat16*)smem;            // phase1 [256][64]
  __hip_bfloat16* Gs = (__hip_bfloat16*)smem;            // phase3 [256][128]
  __hip_bfloat16* Qs = (__hip_bfloat16*)(smem + 65536);  // phase1 [32][64]
  __hip_bfloat16* Ps = (__hip_bfloat16*)(smem + 65536);  // phase3 [32][136]
  float* pred = (float*)(smem + 65536 + 8704);           // [32][8]
  float* rowstat = (float*)(smem + 65536 + 8704 + 1024); // [32]: max, then inv-sum

  const int tid = threadIdx.x;
  const int wid = tid >> 6;
  const int lane = tid & 63;
  const int m = lane & 15, quad = lane >> 4;
  const int b = blockIdx.y;
  const int q0 = blockIdx.x * 32;

  // stage Q (theta cols of pgf), waves 0-3: 8 rows each
  if (wid < 4) {
    const __hip_bfloat16* src =
        pgf + ((size_t)(b * kHW + q0 + wid * 8 + (lane >> 3))) * kNP + (lane & 7) * 8;
    gll16(src, Qs + wid * 8 * 64);
  }

  float4v sc[2][8] = {};
  const __hip_bfloat16* phb = phip + (size_t)b * kP * 64;
  for (int c = 0; c < 4; ++c) {
#pragma unroll
    for (int u = 0; u < 4; ++u)
      gll16(phb + (size_t)(c * 256 + u * 64 + (tid >> 3)) * 64 + (tid & 7) * 8,
            Ks + (u * 64 + wid * 8) * 64);
    __syncthreads();
#pragma unroll
    for (int kk = 0; kk < 64; kk += 32) {
      short8 a[2], bb[2];
#pragma unroll
      for (int i = 0; i < 2; ++i)
        a[i] = *(const short8*)&Qs[(i * 16 + m) * 64 + kk + quad * 8];
#pragma unroll
      for (int j = 0; j < 2; ++j)
        bb[j] = *(const short8*)&Ks[(wid * 32 + j * 16 + m) * 64 + kk + quad * 8];
#pragma unroll
      for (int i = 0; i < 2; ++i)
#pragma unroll
        for (int j = 0; j < 2; ++j)
          sc[i][c * 2 + j] = mfma16(a[i], bb[j], sc[i][c * 2 + j]);
    }
    __syncthreads();
  }

  // ---- softmax (exact, unnormalized P) ----
  float mx[2][4];
#pragma unroll
  for (int i = 0; i < 2; ++i)
#pragma unroll
    for (int r = 0; r < 4; ++r) {
      float v = sc[i][0][r];
#pragma unroll
      for (int s = 1; s < 8; ++s) v = fmaxf(v, sc[i][s][r]);
#pragma unroll
      for (int d = 1; d < 16; d <<= 1) v = fmaxf(v, __shfl_xor(v, d));
      mx[i][r] = v;
    }
  if (m == 0) {
#pragma unroll
    for (int i = 0; i < 2; ++i)
#pragma unroll
      for (int r = 0; r < 4; ++r) pred[(i * 16 + quad * 4 + r) * 8 + wid] = mx[i][r];
  }
  __syncthreads();
  if (tid < 32) {
    float v = pred[tid * 8];
#pragma unroll
    for (int w = 1; w < 8; ++w) v = fmaxf(v, pred[tid * 8 + w]);
    rowstat[tid] = v;
  }
  __syncthreads();
  float sm[2][4];
#pragma unroll
  for (int i = 0; i < 2; ++i)
#pragma unroll
    for (int r = 0; r < 4; ++r) {
      const float rm = rowstat[i * 16 + quad * 4 + r];
      float s = 0.f;
#pragma unroll
      for (int ss = 0; ss < 8; ++ss) {
        float e = __expf(sc[i][ss][r] - rm);
        sc[i][ss][r] = e;
        s += e;
      }
#pragma unroll
      for (int d = 1; d < 16; d <<= 1) s += __shfl_xor(s, d);
      sm[i][r] = s;
    }
  __syncthreads();  // everyone done reading rowstat(max)
  if (m == 0) {
#pragma unroll
    for (int i = 0; i < 2; ++i)
#pragma unroll
      for (int r = 0; r < 4; ++r) pred[(i * 16 + quad * 4 + r) * 8 + wid] = sm[i][r];
  }
  __syncthreads();
  if (tid < 32) {
    float s = 0.f;
#pragma unroll
    for (int w = 0; w < 8; ++w) s += pred[tid * 8 + w];
    rowstat[tid] = 1.f / s;
  }

  // ---- PV ----
  float4v oc[2][2] = {};
  const __hip_bfloat16* gb = gT + (size_t)b * kCV * kP;
  for (int c2 = 0; c2 < 8; ++c2) {
#pragma unroll
    for (int u = 0; u < 8; ++u)
      gll16(gb + (size_t)(u * 32 + (tid >> 4)) * kP + c2 * 128 + (lane & 15) * 8,
            Gs + (u * 32 + wid * 4) * 128);
    if ((wid >> 2) == (c2 & 1)) {
      const int lc0 = (wid & 3) * 32;
      const int sbase = (c2 >> 1) * 2;
#pragma unroll
      for (int i = 0; i < 2; ++i)
#pragma unroll
        for (int j = 0; j < 2; ++j)
#pragma unroll
          for (int r = 0; r < 4; ++r)
            Ps[(i * 16 + quad * 4 + r) * 136 + lc0 + j * 16 + m] =
                __float2bfloat16(sc[i][sbase + j][r]);
    }
    __syncthreads();
#pragma unroll
    for (int kk = 0; kk < 128; kk += 32) {
      short8 a[2], bb[2];
#pragma unroll
      for (int i = 0; i < 2; ++i)
        a[i] = *(const short8*)&Ps[(i * 16 + m) * 136 + kk + quad * 8];
#pragma unroll
      for (int j = 0; j < 2; ++j)
        bb[j] = *(const short8*)&Gs[(wid * 32 + j * 16 + m) * 128 + kk + quad * 8];
#pragma unroll
      for (int i = 0; i < 2; ++i)
#pragma unroll
        for (int j = 0; j < 2; ++j) oc[i][j] = mfma16(a[i], bb[j], oc[i][j]);
    }
    __syncthreads();
  }
  // store O scaled by inverse row sum
#pragma unroll
  for (int i = 0; i < 2; ++i)
#pragma unroll
    for (int j = 0; j < 2; ++j)
#pragma unroll
      for (int r = 0; r < 4; ++r) {
        const int row = i * 16 + quad * 4 + r;
        O[((size_t)b * kHW + q0 + row) * kCV + wid * 32 + j * 16 + m] =
            __float2bfloat16(oc[i][j][r] * rowstat[row]);
      }
}

extern "C" void kernel_launch(void* const* d_in, const int* in_sizes, int n_in,
                              void* d_out, int out_size, void* d_ws, size_t ws_size,
                              hipStream_t stream) {
  (void)in_sizes; (void)n_in; (void)out_size; (void)ws_size;
  const float* x     = (const float*)d_in[0];
  const float* wt    = (const float*)d_in[1];
  const float* wphi  = (const float*)d_in[2];
  const float* wg    = (const float*)d_in[3];
  const float* wo    = (const float*)d_in[4];
  const float* wo_g  = (const float*)d_in[5];  // gamma
  float* out = (float*)d_out;

  char* ws = (char*)d_ws;
  __hip_bfloat16* xbf  = (__hip_bfloat16*)(ws);              // 33,554,432 B
  __hip_bfloat16* wAll = (__hip_bfloat16*)(ws + 33554432);   //    393,216 B
  __hip_bfloat16* woT  = (__hip_bfloat16*)(ws + 33947648);   //    262,144 B
  __hip_bfloat16* pgf  = (__hip_bfloat16*)(ws + 34209792);   // 25,165,824 B
  __hip_bfloat16* phip = (__hip_bfloat16*)(ws + 59375616);   //  1,048,576 B
  __hip_bfloat16* gT   = (__hip_bfloat16*)(ws + 60424192);   //  4,194,304 B
  __hip_bfloat16* O    = xbf;  // alias: xbf dead after proj GEMM (16.7 MB used)

  k_cast_x<<<8192, 256, 0, stream>>>(x, xbf);
  k_pack_w<<<1280, 256, 0, stream>>>(wt, wphi, wg, wo, wAll, woT);
  // pgf = x @ [w_theta|w_phi|w_g] : [32768 x 384]
  gemm_bt<128, 128, 2, 2, EPI_BF16><<<dim3(256, 3), 256, 0, stream>>>(
      xbf, wAll, pgf, 32768, kNP, 512, nullptr, nullptr);
  k_pool_phi<<<2048, 256, 0, stream>>>(pgf, phip);
  k_pool_gT<<<dim3(16, 4, 8), 256, 0, stream>>>(pgf, gT);
  k_fattn<<<dim3(kHW / 32, kB), 512, 0, stream>>>(pgf, phip, gT, O);
  // out = x + gamma * (O @ w_o) : [32768 x 512]
  gemm_bt<128, 128, 2, 2, EPI_RESID><<<dim3(256, 4), 256, 0, stream>>>(
      O, woT, out, 32768, kC, kCV, x, wo_g);
}

// Round 4
// 257.648 us; speedup vs baseline: 10.5779x; 1.0212x over previous
//
#include <hip/hip_runtime.h>
#include <hip/hip_bf16.h>
#include <cstddef>
#include <cstdint>

// SelfAttn (SAGAN) — Round 4: XOR-swizzled LDS (bank-conflict-free), dbuf chunks,
// fp32-direct projection (cast kernel eliminated).
// pack -> proj GEMM [32768x384] -> pools -> fused attn -> out GEMM(+resid)

typedef __attribute__((ext_vector_type(8))) short short8;
typedef __attribute__((ext_vector_type(4))) float float4v;

namespace {
constexpr int kB = 8, kC = 512, kCK = 64, kCV = 256, kHW = 4096, kP = 1024;
constexpr int kNP = 384;  // packed projection width [theta|phi|g]
}

__device__ __forceinline__ void gll16(const void* g, void* l) {
  __builtin_amdgcn_global_load_lds((uint32_t __attribute__((address_space(1)))*)g,
                                   (uint32_t __attribute__((address_space(3)))*)l,
                                   16, 0, 0);
}
__device__ __forceinline__ float4v mfma16(short8 a, short8 b, float4v c) {
  return __builtin_amdgcn_mfma_f32_16x16x32_bf16(a, b, c, 0, 0, 0);
}
// bf16 tile row = 128B (8 octs of 16B), slot swizzle oct^ (row&7)
__device__ __forceinline__ const short8* fragp(const char* tile, int row, int oct) {
  return (const short8*)(tile + row * 128 + ((oct ^ (row & 7)) * 16));
}

// pack weights: wAll[384][512] = [theta|phi|g]^T; woT[512][256]
__global__ __launch_bounds__(256) void k_pack_w(
    const float* __restrict__ wt, const float* __restrict__ wphi,
    const float* __restrict__ wg, const float* __restrict__ wo,
    __hip_bfloat16* __restrict__ wAll, __hip_bfloat16* __restrict__ woT) {
  int idx = blockIdx.x * 256 + threadIdx.x;  // 327680
  if (idx < 196608) {
    int n = idx >> 9, k = idx & 511;
    float v = (n < 64) ? wt[k * 64 + n]
            : (n < 128) ? wphi[k * 64 + (n - 64)]
                        : wg[k * 256 + (n - 128)];
    wAll[idx] = __float2bfloat16(v);
  } else {
    int t = idx - 196608;
    int n = t >> 8, k = t & 255;
    woT[t] = __float2bfloat16(wo[k * 512 + n]);
  }
}

// ---- proj: pgf[32768][384] = bf16(x) @ wAll^T, A fp32 read direct, tile 64x384 ----
__global__ __launch_bounds__(256) void k_proj(const float* __restrict__ x,
                                              const __hip_bfloat16* __restrict__ wAll,
                                              __hip_bfloat16* __restrict__ pgf) {
  __shared__ __align__(16) char smem[16384 + 49152];
  char* As = smem;           // fp32 [64 rows][16 sq of 16B], swizzle sq^(row&15)
  char* Bs = smem + 16384;   // bf16 [384 rows][8 oct], swizzle oct^(row&7)
  const int tid = threadIdx.x, wid = tid >> 6, lane = tid & 63;
  const int m = lane & 15, quad = lane >> 4;
  const int row0 = blockIdx.x * 64;
  const int wm = (wid >> 1) * 32, wn = (wid & 1) * 192;
  float4v acc[2][12] = {};
  for (int kc = 0; kc < 512; kc += 64) {
#pragma unroll
    for (int u = 0; u < 4; ++u) {  // A: region = 4 rows x 16 sq (1KB)
      const int r0 = (wid * 4 + u) * 4;
      const int row = r0 + (lane >> 4);
      const int sqg = (lane & 15) ^ (row & 15);
      gll16(x + (size_t)(row0 + row) * 512 + kc + sqg * 4, As + r0 * 256);
    }
#pragma unroll
    for (int u = 0; u < 12; ++u) {  // B: region = 8 rows x 8 oct (1KB)
      const int r0 = (wid * 12 + u) * 8;
      const int row = r0 + (lane >> 3);
      const int og = (lane & 7) ^ (row & 7);
      gll16(wAll + (size_t)row * 512 + kc + og * 8, Bs + r0 * 128);
    }
    __syncthreads();
#pragma unroll
    for (int kk = 0; kk < 64; kk += 32) {
      short8 af[2];
#pragma unroll
      for (int i = 0; i < 2; ++i) {
        const int row = wm + i * 16 + m;
        const int sq0 = (kk >> 2) + quad * 2;
        float4v lo = *(const float4v*)(As + row * 256 + ((sq0 ^ m) * 16));
        float4v hi = *(const float4v*)(As + row * 256 + (((sq0 + 1) ^ m) * 16));
        short8 a;
        a[0] = __builtin_bit_cast(short, __float2bfloat16(lo[0]));
        a[1] = __builtin_bit_cast(short, __float2bfloat16(lo[1]));
        a[2] = __builtin_bit_cast(short, __float2bfloat16(lo[2]));
        a[3] = __builtin_bit_cast(short, __float2bfloat16(lo[3]));
        a[4] = __builtin_bit_cast(short, __float2bfloat16(hi[0]));
        a[5] = __builtin_bit_cast(short, __float2bfloat16(hi[1]));
        a[6] = __builtin_bit_cast(short, __float2bfloat16(hi[2]));
        a[7] = __builtin_bit_cast(short, __float2bfloat16(hi[3]));
        af[i] = a;
      }
      const int oct = (kk >> 3) + quad;
#pragma unroll
      for (int j = 0; j < 12; ++j) {
        short8 bf = *fragp(Bs, wn + j * 16 + m, oct);
#pragma unroll
        for (int i = 0; i < 2; ++i) acc[i][j] = mfma16(af[i], bf, acc[i][j]);
      }
    }
    __syncthreads();
  }
#pragma unroll
  for (int i = 0; i < 2; ++i)
#pragma unroll
    for (int j = 0; j < 12; ++j)
#pragma unroll
      for (int r = 0; r < 4; ++r)
        pgf[(size_t)(row0 + wm + i * 16 + quad * 4 + r) * 384 + wn + j * 16 + m] =
            __float2bfloat16(acc[i][j][r]);
}

// phi_p[b][p][c] = max 2x2 of pgf[b,h,w,64+c]
__global__ __launch_bounds__(256) void k_pool_phi(const __hip_bfloat16* __restrict__ pg,
                                                  __hip_bfloat16* __restrict__ phi_p) {
  int idx = blockIdx.x * 256 + threadIdx.x;  // 524288
  int c = idx & 63;
  int p = (idx >> 6) & 1023;
  int b = idx >> 16;
  int ph = p >> 5, pw = p & 31;
  size_t base = ((size_t)b * 4096 + ph * 128 + pw * 2) * kNP + 64 + c;
  float v0 = __bfloat162float(pg[base]);
  float v1 = __bfloat162float(pg[base + kNP]);
  float v2 = __bfloat162float(pg[base + kNP * 64]);
  float v3 = __bfloat162float(pg[base + kNP * 64 + kNP]);
  phi_p[idx] = __float2bfloat16(fmaxf(fmaxf(v0, v1), fmaxf(v2, v3)));
}

// gT[b][v][p] = max 2x2 of pgf[b,h,w,128+v]
__global__ __launch_bounds__(256) void k_pool_gT(const __hip_bfloat16* __restrict__ pg,
                                                 __hip_bfloat16* __restrict__ gT) {
  __shared__ __hip_bfloat16 t[64][65];
  const int p0 = blockIdx.x * 64, v0 = blockIdx.y * 64, b = blockIdx.z;
#pragma unroll
  for (int it = 0; it < 16; ++it) {
    int li = it * 256 + threadIdx.x;
    int pp = li >> 6, v = li & 63;
    int p = p0 + pp;
    int ph = p >> 5, pw = p & 31;
    size_t base = ((size_t)b * 4096 + ph * 128 + pw * 2) * kNP + 128 + v0 + v;
    float mv = fmaxf(
        fmaxf(__bfloat162float(pg[base]), __bfloat162float(pg[base + kNP])),
        fmaxf(__bfloat162float(pg[base + kNP * 64]), __bfloat162float(pg[base + kNP * 64 + kNP])));
    t[pp][v] = __float2bfloat16(mv);
  }
  __syncthreads();
#pragma unroll
  for (int it = 0; it < 16; ++it) {
    int li = it * 256 + threadIdx.x;
    int v = li >> 6, p = li & 63;
    gT[((size_t)b * 256 + v0 + v) * 1024 + p0 + p] = t[p][v];
  }
}

// ---- fused attention: 32 Q rows/block, 512 thr, dbuf chunks, swizzled LDS ----
__global__ __launch_bounds__(512, 4) void k_fattn(
    const __hip_bfloat16* __restrict__ pgf,   // [B*4096][384], theta cols 0..63
    const __hip_bfloat16* __restrict__ phip,  // [B][1024][64]
    const __hip_bfloat16* __restrict__ gT,    // [B][256][1024]
    __hip_bfloat16* __restrict__ O) {         // [B][4096][256]
  __shared__ __align__(16) char smem[65536 + 8192 + 1024 + 128];
  char* KG = smem;               // dbuf 2 x 32KB: Ks (phase1) / Gs (phase3)
  char* PQ = smem + 65536;       // Qs 4KB (phase1) overlaid by Ps[2] 2x4KB (phase3)
  float* pred = (float*)(smem + 65536 + 8192);     // [32][8]
  float* rowstat = (float*)(smem + 65536 + 8192 + 1024);  // [32]

  const int tid = threadIdx.x, wid = tid >> 6, lane = tid & 63;
  const int m = lane & 15, quad = lane >> 4;
  const int b = blockIdx.y, q0 = blockIdx.x * 32;

  // stage Q [32][64] (waves 0-3, 8 rows each, swizzled)
  if (wid < 4) {
    const int row = wid * 8 + (lane >> 3);
    const int og = (lane & 7) ^ (row & 7);
    gll16(pgf + (size_t)(b * kHW + q0 + row) * kNP + og * 8, PQ + wid * 8 * 128);
  }
  const __hip_bfloat16* phb = phip + (size_t)b * kP * 64;
  auto stageK = [&](int c, int buf) {
#pragma unroll
    for (int u = 0; u < 4; ++u) {
      const int r0 = wid * 32 + u * 8;
      const int row = r0 + (lane >> 3);
      const int og = (lane & 7) ^ (row & 7);
      gll16(phb + (size_t)(c * 256 + row) * 64 + og * 8, KG + buf * 32768 + r0 * 128);
    }
  };
  stageK(0, 0);
  __syncthreads();

  float4v sc[2][8] = {};
#pragma unroll
  for (int c = 0; c < 4; ++c) {
    if (c < 3) stageK(c + 1, (c + 1) & 1);
    const char* Kb = KG + (c & 1) * 32768;
#pragma unroll
    for (int kk = 0; kk < 64; kk += 32) {
      const int oct = (kk >> 3) + quad;
      short8 a[2], bb[2];
#pragma unroll
      for (int i = 0; i < 2; ++i) a[i] = *fragp(PQ, i * 16 + m, oct);
#pragma unroll
      for (int j = 0; j < 2; ++j) bb[j] = *fragp(Kb, wid * 32 + j * 16 + m, oct);
#pragma unroll
      for (int i = 0; i < 2; ++i)
#pragma unroll
        for (int j = 0; j < 2; ++j) sc[i][c * 2 + j] = mfma16(a[i], bb[j], sc[i][c * 2 + j]);
    }
    __syncthreads();
  }

  // ---- softmax (exact; P left unnormalized, 1/sum folded into epilogue) ----
  float mx[2][4];
#pragma unroll
  for (int i = 0; i < 2; ++i)
#pragma unroll
    for (int r = 0; r < 4; ++r) {
      float v = sc[i][0][r];
#pragma unroll
      for (int s = 1; s < 8; ++s) v = fmaxf(v, sc[i][s][r]);
#pragma unroll
      for (int d = 1; d < 16; d <<= 1) v = fmaxf(v, __shfl_xor(v, d));
      mx[i][r] = v;
    }
  if (m == 0) {
#pragma unroll
    for (int i = 0; i < 2; ++i)
#pragma unroll
      for (int r = 0; r < 4; ++r) pred[(i * 16 + quad * 4 + r) * 8 + wid] = mx[i][r];
  }
  __syncthreads();
  if (tid < 32) {
    float v = pred[tid * 8];
#pragma unroll
    for (int w = 1; w < 8; ++w) v = fmaxf(v, pred[tid * 8 + w]);
    rowstat[tid] = v;
  }
  __syncthreads();
  float sm[2][4];
#pragma unroll
  for (int i = 0; i < 2; ++i)
#pragma unroll
    for (int r = 0; r < 4; ++r) {
      const float rm = rowstat[i * 16 + quad * 4 + r];
      float s = 0.f;
#pragma unroll
      for (int ss = 0; ss < 8; ++ss) {
        float e = __expf(sc[i][ss][r] - rm);
        sc[i][ss][r] = e;
        s += e;
      }
#pragma unroll
      for (int d = 1; d < 16; d <<= 1) s += __shfl_xor(s, d);
      sm[i][r] = s;
    }
  __syncthreads();
  if (m == 0) {
#pragma unroll
    for (int i = 0; i < 2; ++i)
#pragma unroll
      for (int r = 0; r < 4; ++r) pred[(i * 16 + quad * 4 + r) * 8 + wid] = sm[i][r];
  }
  __syncthreads();
  if (tid < 32) {
    float s = 0.f;
#pragma unroll
    for (int w = 0; w < 8; ++w) s += pred[tid * 8 + w];
    rowstat[tid] = 1.f / s;
  }

  // ---- PV: 16 chunks of 64 p, dbuf Gs + dbuf Ps ----
  const __hip_bfloat16* gb = gT + (size_t)b * kCV * kP;
  auto stageG = [&](int cp, int buf) {
#pragma unroll
    for (int u = 0; u < 4; ++u) {
      const int r0 = wid * 32 + u * 8;     // v row
      const int row = r0 + (lane >> 3);
      const int og = (lane & 7) ^ (row & 7);
      gll16(gb + (size_t)row * kP + cp * 64 + og * 8, KG + buf * 32768 + r0 * 128);
    }
  };
  auto writeP = [&](int cp, int pbuf) {
    if ((wid >> 1) == (cp & 3)) {
      const int c = cp >> 2;
#pragma unroll
      for (int i = 0; i < 2; ++i)
#pragma unroll
        for (int jl = 0; jl < 2; ++jl) {
          const int pl = (wid & 1) * 32 + jl * 16 + m;
#pragma unroll
          for (int r = 0; r < 4; ++r) {
            const int row = i * 16 + quad * 4 + r;
            *(__hip_bfloat16*)(PQ + pbuf * 4096 + row * 128 +
                               (((pl >> 3) ^ (row & 7)) * 16) + (pl & 7) * 2) =
                __float2bfloat16(sc[i][c * 2 + jl][r]);
          }
        }
    }
  };
  writeP(0, 0);
  stageG(0, 0);
  __syncthreads();

  float4v oc[2][2] = {};
#pragma unroll
  for (int cp = 0; cp < 16; ++cp) {
    if (cp < 15) {
      stageG(cp + 1, (cp + 1) & 1);
      writeP(cp + 1, (cp + 1) & 1);
    }
    const char* Gb = KG + (cp & 1) * 32768;
    const char* Pb = PQ + (cp & 1) * 4096;
#pragma unroll
    for (int kk = 0; kk < 64; kk += 32) {
      const int oct = (kk >> 3) + quad;
      short8 a[2], bb[2];
#pragma unroll
      for (int i = 0; i < 2; ++i) a[i] = *fragp(Pb, i * 16 + m, oct);
#pragma unroll
      for (int j = 0; j < 2; ++j) bb[j] = *fragp(Gb, wid * 32 + j * 16 + m, oct);
#pragma unroll
      for (int i = 0; i < 2; ++i)
#pragma unroll
        for (int j = 0; j < 2; ++j) oc[i][j] = mfma16(a[i], bb[j], oc[i][j]);
    }
    __syncthreads();
  }
#pragma unroll
  for (int i = 0; i < 2; ++i)
#pragma unroll
    for (int j = 0; j < 2; ++j)
#pragma unroll
      for (int r = 0; r < 4; ++r) {
        const int row = i * 16 + quad * 4 + r;
        O[((size_t)b * kHW + q0 + row) * kCV + wid * 32 + j * 16 + m] =
            __float2bfloat16(oc[i][j][r] * rowstat[row]);
      }
}

// ---- out = x + gamma * (O @ w_o), tile 128x128, dbuf, swizzled ----
__global__ __launch_bounds__(256) void k_out(const __hip_bfloat16* __restrict__ A,
                                             const __hip_bfloat16* __restrict__ Bw,
                                             const float* __restrict__ x,
                                             const float* __restrict__ gamma,
                                             float* __restrict__ out) {
  __shared__ __align__(16) char smem[4 * 16384];  // As[2] then Bs[2]
  const int tid = threadIdx.x, wid = tid >> 6, lane = tid & 63;
  const int m = lane & 15, quad = lane >> 4;
  const int row0 = blockIdx.x * 128, col0 = blockIdx.y * 128;
  const int wm = (wid >> 1) * 64, wn = (wid & 1) * 64;
  float4v acc[4][4] = {};
  auto stage = [&](int t, int buf) {
    const int kc = t * 64;
#pragma unroll
    for (int u = 0; u < 4; ++u) {
      const int r0 = (wid * 4 + u) * 8;
      const int row = r0 + (lane >> 3);
      const int og = (lane & 7) ^ (row & 7);
      gll16(A + (size_t)(row0 + row) * 256 + kc + og * 8, smem + buf * 16384 + r0 * 128);
      gll16(Bw + (size_t)(col0 + row) * 256 + kc + og * 8,
            smem + 32768 + buf * 16384 + r0 * 128);
    }
  };
  stage(0, 0);
  __syncthreads();
#pragma unroll
  for (int t = 0; t < 4; ++t) {
    if (t < 3) stage(t + 1, (t + 1) & 1);
    const char* Ab = smem + (t & 1) * 16384;
    const char* Bb = smem + 32768 + (t & 1) * 16384;
#pragma unroll
    for (int kk = 0; kk < 64; kk += 32) {
      const int oct = (kk >> 3) + quad;
      short8 af[4], bf[4];
#pragma unroll
      for (int i = 0; i < 4; ++i) af[i] = *fragp(Ab, wm + i * 16 + m, oct);
#pragma unroll
      for (int j = 0; j < 4; ++j) bf[j] = *fragp(Bb, wn + j * 16 + m, oct);
#pragma unroll
      for (int i = 0; i < 4; ++i)
#pragma unroll
        for (int j = 0; j < 4; ++j) acc[i][j] = mfma16(af[i], bf[j], acc[i][j]);
    }
    __syncthreads();
  }
  const float g = gamma[0];
#pragma unroll
  for (int i = 0; i < 4; ++i)
#pragma unroll
    for (int j = 0; j < 4; ++j) {
      const int cc = col0 + wn + j * 16 + m;
      const int rb = row0 + wm + i * 16 + quad * 4;
#pragma unroll
      for (int r = 0; r < 4; ++r) {
        const size_t idx = (size_t)(rb + r) * 512 + cc;
        out[idx] = x[idx] + g * acc[i][j][r];
      }
    }
}

extern "C" void kernel_launch(void* const* d_in, const int* in_sizes, int n_in,
                              void* d_out, int out_size, void* d_ws, size_t ws_size,
                              hipStream_t stream) {
  (void)in_sizes; (void)n_in; (void)out_size; (void)ws_size;
  const float* x     = (const float*)d_in[0];
  const float* wt    = (const float*)d_in[1];
  const float* wphi  = (const float*)d_in[2];
  const float* wg    = (const float*)d_in[3];
  const float* wo    = (const float*)d_in[4];
  const float* gamma = (const float*)d_in[5];
  float* out = (float*)d_out;

  char* ws = (char*)d_ws;
  __hip_bfloat16* wAll = (__hip_bfloat16*)(ws);              //    393,216
  __hip_bfloat16* woT  = (__hip_bfloat16*)(ws + 393216);     //    262,144
  __hip_bfloat16* pgf  = (__hip_bfloat16*)(ws + 655360);     // 25,165,824
  __hip_bfloat16* phip = (__hip_bfloat16*)(ws + 25821184);   //  1,048,576
  __hip_bfloat16* gT   = (__hip_bfloat16*)(ws + 26869760);   //  4,194,304
  __hip_bfloat16* O    = (__hip_bfloat16*)(ws + 31064064);   // 16,777,216  (total 47.8MB)

  k_pack_w<<<1280, 256, 0, stream>>>(wt, wphi, wg, wo, wAll, woT);
  k_proj<<<512, 256, 0, stream>>>(x, wAll, pgf);
  k_pool_phi<<<2048, 256, 0, stream>>>(pgf, phip);
  k_pool_gT<<<dim3(16, 4, 8), 256, 0, stream>>>(pgf, gT);
  k_fattn<<<dim3(kHW / 32, kB), 512, 0, stream>>>(pgf, phip, gT, O);
  k_out<<<dim3(256, 4), 256, 0, stream>>>(O, woT, x, gamma, out);
}

// Round 5
// 234.868 us; speedup vs baseline: 11.6038x; 1.0970x over previous
//
#include <hip/hip_runtime.h>
#include <hip/hip_bf16.h>
#include <cstddef>
#include <cstdint>

// SelfAttn (SAGAN) — Round 5: fattn = R3 chunk structure + XOR-swizzled LDS.
// pack -> proj GEMM [32768x384] -> pools -> fused attn -> out GEMM(+resid)

typedef __attribute__((ext_vector_type(8))) short short8;
typedef __attribute__((ext_vector_type(4))) float float4v;

namespace {
constexpr int kB = 8, kC = 512, kCK = 64, kCV = 256, kHW = 4096, kP = 1024;
constexpr int kNP = 384;  // packed projection width [theta|phi|g]
}

__device__ __forceinline__ void gll16(const void* g, void* l) {
  __builtin_amdgcn_global_load_lds((uint32_t __attribute__((address_space(1)))*)g,
                                   (uint32_t __attribute__((address_space(3)))*)l,
                                   16, 0, 0);
}
__device__ __forceinline__ float4v mfma16(short8 a, short8 b, float4v c) {
  return __builtin_amdgcn_mfma_f32_16x16x32_bf16(a, b, c, 0, 0, 0);
}
// bf16 tile row = 128B (8 octs of 16B), slot swizzle oct ^ (row&7)
__device__ __forceinline__ const short8* fragp(const char* tile, int row, int oct) {
  return (const short8*)(tile + row * 128 + ((oct ^ (row & 7)) * 16));
}
// bf16 tile row = 256B (16 octs of 16B), slot swizzle oct ^ (row&15)
__device__ __forceinline__ const short8* fragp16(const char* tile, int row, int oct) {
  return (const short8*)(tile + row * 256 + ((oct ^ (row & 15)) * 16));
}

// pack weights: wAll[384][512] = [theta|phi|g]^T; woT[512][256]
__global__ __launch_bounds__(256) void k_pack_w(
    const float* __restrict__ wt, const float* __restrict__ wphi,
    const float* __restrict__ wg, const float* __restrict__ wo,
    __hip_bfloat16* __restrict__ wAll, __hip_bfloat16* __restrict__ woT) {
  int idx = blockIdx.x * 256 + threadIdx.x;  // 327680
  if (idx < 196608) {
    int n = idx >> 9, k = idx & 511;
    float v = (n < 64) ? wt[k * 64 + n]
            : (n < 128) ? wphi[k * 64 + (n - 64)]
                        : wg[k * 256 + (n - 128)];
    wAll[idx] = __float2bfloat16(v);
  } else {
    int t = idx - 196608;
    int n = t >> 8, k = t & 255;
    woT[t] = __float2bfloat16(wo[k * 512 + n]);
  }
}

// ---- proj: pgf[32768][384] = bf16(x) @ wAll^T, A fp32 read direct, tile 64x384 ----
__global__ __launch_bounds__(256) void k_proj(const float* __restrict__ x,
                                              const __hip_bfloat16* __restrict__ wAll,
                                              __hip_bfloat16* __restrict__ pgf) {
  __shared__ __align__(16) char smem[16384 + 49152];
  char* As = smem;           // fp32 [64 rows][16 sq of 16B], swizzle sq^(row&15)
  char* Bs = smem + 16384;   // bf16 [384 rows][8 oct], swizzle oct^(row&7)
  const int tid = threadIdx.x, wid = tid >> 6, lane = tid & 63;
  const int m = lane & 15, quad = lane >> 4;
  const int row0 = blockIdx.x * 64;
  const int wm = (wid >> 1) * 32, wn = (wid & 1) * 192;
  float4v acc[2][12] = {};
  for (int kc = 0; kc < 512; kc += 64) {
#pragma unroll
    for (int u = 0; u < 4; ++u) {  // A: region = 4 rows x 16 sq (1KB)
      const int r0 = (wid * 4 + u) * 4;
      const int row = r0 + (lane >> 4);
      const int sqg = (lane & 15) ^ (row & 15);
      gll16(x + (size_t)(row0 + row) * 512 + kc + sqg * 4, As + r0 * 256);
    }
#pragma unroll
    for (int u = 0; u < 12; ++u) {  // B: region = 8 rows x 8 oct (1KB)
      const int r0 = (wid * 12 + u) * 8;
      const int row = r0 + (lane >> 3);
      const int og = (lane & 7) ^ (row & 7);
      gll16(wAll + (size_t)row * 512 + kc + og * 8, Bs + r0 * 128);
    }
    __syncthreads();
#pragma unroll
    for (int kk = 0; kk < 64; kk += 32) {
      short8 af[2];
#pragma unroll
      for (int i = 0; i < 2; ++i) {
        const int row = wm + i * 16 + m;
        const int sq0 = (kk >> 2) + quad * 2;
        float4v lo = *(const float4v*)(As + row * 256 + ((sq0 ^ m) * 16));
        float4v hi = *(const float4v*)(As + row * 256 + (((sq0 + 1) ^ m) * 16));
        short8 a;
        a[0] = __builtin_bit_cast(short, __float2bfloat16(lo[0]));
        a[1] = __builtin_bit_cast(short, __float2bfloat16(lo[1]));
        a[2] = __builtin_bit_cast(short, __float2bfloat16(lo[2]));
        a[3] = __builtin_bit_cast(short, __float2bfloat16(lo[3]));
        a[4] = __builtin_bit_cast(short, __float2bfloat16(hi[0]));
        a[5] = __builtin_bit_cast(short, __float2bfloat16(hi[1]));
        a[6] = __builtin_bit_cast(short, __float2bfloat16(hi[2]));
        a[7] = __builtin_bit_cast(short, __float2bfloat16(hi[3]));
        af[i] = a;
      }
      const int oct = (kk >> 3) + quad;
#pragma unroll
      for (int j = 0; j < 12; ++j) {
        short8 bf = *fragp(Bs, wn + j * 16 + m, oct);
#pragma unroll
        for (int i = 0; i < 2; ++i) acc[i][j] = mfma16(af[i], bf, acc[i][j]);
      }
    }
    __syncthreads();
  }
#pragma unroll
  for (int i = 0; i < 2; ++i)
#pragma unroll
    for (int j = 0; j < 12; ++j)
#pragma unroll
      for (int r = 0; r < 4; ++r)
        pgf[(size_t)(row0 + wm + i * 16 + quad * 4 + r) * 384 + wn + j * 16 + m] =
            __float2bfloat16(acc[i][j][r]);
}

// phi_p[b][p][c] = max 2x2 of pgf[b,h,w,64+c]
__global__ __launch_bounds__(256) void k_pool_phi(const __hip_bfloat16* __restrict__ pg,
                                                  __hip_bfloat16* __restrict__ phi_p) {
  int idx = blockIdx.x * 256 + threadIdx.x;  // 524288
  int c = idx & 63;
  int p = (idx >> 6) & 1023;
  int b = idx >> 16;
  int ph = p >> 5, pw = p & 31;
  size_t base = ((size_t)b * 4096 + ph * 128 + pw * 2) * kNP + 64 + c;
  float v0 = __bfloat162float(pg[base]);
  float v1 = __bfloat162float(pg[base + kNP]);
  float v2 = __bfloat162float(pg[base + kNP * 64]);
  float v3 = __bfloat162float(pg[base + kNP * 64 + kNP]);
  phi_p[idx] = __float2bfloat16(fmaxf(fmaxf(v0, v1), fmaxf(v2, v3)));
}

// gT[b][v][p] = max 2x2 of pgf[b,h,w,128+v]
__global__ __launch_bounds__(256) void k_pool_gT(const __hip_bfloat16* __restrict__ pg,
                                                 __hip_bfloat16* __restrict__ gT) {
  __shared__ __hip_bfloat16 t[64][65];
  const int p0 = blockIdx.x * 64, v0 = blockIdx.y * 64, b = blockIdx.z;
#pragma unroll
  for (int it = 0; it < 16; ++it) {
    int li = it * 256 + threadIdx.x;
    int pp = li >> 6, v = li & 63;
    int p = p0 + pp;
    int ph = p >> 5, pw = p & 31;
    size_t base = ((size_t)b * 4096 + ph * 128 + pw * 2) * kNP + 128 + v0 + v;
    float mv = fmaxf(
        fmaxf(__bfloat162float(pg[base]), __bfloat162float(pg[base + kNP])),
        fmaxf(__bfloat162float(pg[base + kNP * 64]), __bfloat162float(pg[base + kNP * 64 + kNP])));
    t[pp][v] = __float2bfloat16(mv);
  }
  __syncthreads();
#pragma unroll
  for (int it = 0; it < 16; ++it) {
    int li = it * 256 + threadIdx.x;
    int v = li >> 6, p = li & 63;
    gT[((size_t)b * 256 + v0 + v) * 1024 + p0 + p] = t[p][v];
  }
}

// ---- fused attention: 32 Q rows/block, 512 thr, swizzled LDS ----
// Phase1: 4 key-chunks of 256 (dbuf 2x32KB, 1 barrier/chunk).
// Phase3: 8 p-chunks of 128 (single 64KB Gs, Ps[32][128] swizzle16, 2 barriers/chunk).
__global__ __launch_bounds__(512) void k_fattn(
    const __hip_bfloat16* __restrict__ pgf,   // [B*4096][384], theta cols 0..63
    const __hip_bfloat16* __restrict__ phip,  // [B][1024][64]
    const __hip_bfloat16* __restrict__ gT,    // [B][256][1024]
    __hip_bfloat16* __restrict__ O) {         // [B][4096][256]
  __shared__ __align__(16) char smem[65536 + 8192 + 1024 + 128];
  char* KG = smem;               // phase1: dbuf Ks 2x32KB; phase3: Gs [256][128] 64KB
  char* PQ = smem + 65536;       // phase1: Qs [32][64] 4KB; phase3: Ps [32][128] 8KB
  float* pred = (float*)(smem + 65536 + 8192);            // [32][8]
  float* rowstat = (float*)(smem + 65536 + 8192 + 1024);  // [32]

  const int tid = threadIdx.x, wid = tid >> 6, lane = tid & 63;
  const int m = lane & 15, quad = lane >> 4;
  const int b = blockIdx.y, q0 = blockIdx.x * 32;

  // stage Q [32][64] (waves 0-3, 8 rows each, swizzled)
  if (wid < 4) {
    const int row = wid * 8 + (lane >> 3);
    const int og = (lane & 7) ^ (row & 7);
    gll16(pgf + (size_t)(b * kHW + q0 + row) * kNP + og * 8, PQ + wid * 8 * 128);
  }
  const __hip_bfloat16* phb = phip + (size_t)b * kP * 64;
  auto stageK = [&](int c, int buf) {
#pragma unroll
    for (int u = 0; u < 4; ++u) {
      const int r0 = wid * 32 + u * 8;
      const int row = r0 + (lane >> 3);
      const int og = (lane & 7) ^ (row & 7);
      gll16(phb + (size_t)(c * 256 + row) * 64 + og * 8, KG + buf * 32768 + r0 * 128);
    }
  };
  stageK(0, 0);
  __syncthreads();

  float4v sc[2][8] = {};
#pragma unroll
  for (int c = 0; c < 4; ++c) {
    if (c < 3) stageK(c + 1, (c + 1) & 1);
    const char* Kb = KG + (c & 1) * 32768;
#pragma unroll
    for (int kk = 0; kk < 64; kk += 32) {
      const int oct = (kk >> 3) + quad;
      short8 a[2], bb[2];
#pragma unroll
      for (int i = 0; i < 2; ++i) a[i] = *fragp(PQ, i * 16 + m, oct);
#pragma unroll
      for (int j = 0; j < 2; ++j) bb[j] = *fragp(Kb, wid * 32 + j * 16 + m, oct);
#pragma unroll
      for (int i = 0; i < 2; ++i)
#pragma unroll
        for (int j = 0; j < 2; ++j) sc[i][c * 2 + j] = mfma16(a[i], bb[j], sc[i][c * 2 + j]);
    }
    __syncthreads();
  }

  // ---- softmax (exact; P unnormalized, 1/sum folded into epilogue) ----
  float mx[2][4];
#pragma unroll
  for (int i = 0; i < 2; ++i)
#pragma unroll
    for (int r = 0; r < 4; ++r) {
      float v = sc[i][0][r];
#pragma unroll
      for (int s = 1; s < 8; ++s) v = fmaxf(v, sc[i][s][r]);
#pragma unroll
      for (int d = 1; d < 16; d <<= 1) v = fmaxf(v, __shfl_xor(v, d));
      mx[i][r] = v;
    }
  if (m == 0) {
#pragma unroll
    for (int i = 0; i < 2; ++i)
#pragma unroll
      for (int r = 0; r < 4; ++r) pred[(i * 16 + quad * 4 + r) * 8 + wid] = mx[i][r];
  }
  __syncthreads();
  if (tid < 32) {
    float v = pred[tid * 8];
#pragma unroll
    for (int w = 1; w < 8; ++w) v = fmaxf(v, pred[tid * 8 + w]);
    rowstat[tid] = v;
  }
  __syncthreads();
  float sm[2][4];
#pragma unroll
  for (int i = 0; i < 2; ++i)
#pragma unroll
    for (int r = 0; r < 4; ++r) {
      const float rm = rowstat[i * 16 + quad * 4 + r];
      float s = 0.f;
#pragma unroll
      for (int ss = 0; ss < 8; ++ss) {
        float e = __expf(sc[i][ss][r] - rm);
        sc[i][ss][r] = e;
        s += e;
      }
#pragma unroll
      for (int d = 1; d < 16; d <<= 1) s += __shfl_xor(s, d);
      sm[i][r] = s;
    }
  __syncthreads();
  if (m == 0) {
#pragma unroll
    for (int i = 0; i < 2; ++i)
#pragma unroll
      for (int r = 0; r < 4; ++r) pred[(i * 16 + quad * 4 + r) * 8 + wid] = sm[i][r];
  }
  __syncthreads();
  if (tid < 32) {
    float s = 0.f;
#pragma unroll
    for (int w = 0; w < 8; ++w) s += pred[tid * 8 + w];
    rowstat[tid] = 1.f / s;
  }

  // ---- PV: 8 chunks of 128 p, single Gs buffer, swizzle16 ----
  const __hip_bfloat16* gb = gT + (size_t)b * kCV * kP;
  float4v oc[2][2] = {};
  for (int cp = 0; cp < 8; ++cp) {
    __syncthreads();  // prior chunk's reads done (also orders softmax -> writeP)
#pragma unroll
    for (int u = 0; u < 8; ++u) {  // stage Gs[256 v][128 p] = 64KB
      const int r0 = wid * 32 + u * 4;
      const int row = r0 + (lane >> 4);
      const int og = (lane & 15) ^ (row & 15);
      gll16(gb + (size_t)row * kP + cp * 128 + og * 8, KG + r0 * 256);
    }
    if ((wid >> 2) == (cp & 1)) {  // write Ps[32][128] (4 waves)
      const int c = cp >> 1;
#pragma unroll
      for (int i = 0; i < 2; ++i)
#pragma unroll
        for (int jl = 0; jl < 2; ++jl) {
          const int pl = (wid & 3) * 32 + jl * 16 + m;
#pragma unroll
          for (int r = 0; r < 4; ++r) {
            const int row = i * 16 + quad * 4 + r;
            *(__hip_bfloat16*)(PQ + row * 256 + (((pl >> 3) ^ (row & 15)) * 16) +
                               (pl & 7) * 2) = __float2bfloat16(sc[i][c * 2 + jl][r]);
          }
        }
    }
    __syncthreads();
#pragma unroll
    for (int kk = 0; kk < 128; kk += 32) {
      const int oct = (kk >> 3) + quad;
      short8 a[2], bb[2];
#pragma unroll
      for (int i = 0; i < 2; ++i) a[i] = *fragp16(PQ, i * 16 + m, oct);
#pragma unroll
      for (int j = 0; j < 2; ++j) bb[j] = *fragp16(KG, wid * 32 + j * 16 + m, oct);
#pragma unroll
      for (int i = 0; i < 2; ++i)
#pragma unroll
        for (int j = 0; j < 2; ++j) oc[i][j] = mfma16(a[i], bb[j], oc[i][j]);
    }
  }
#pragma unroll
  for (int i = 0; i < 2; ++i)
#pragma unroll
    for (int j = 0; j < 2; ++j)
#pragma unroll
      for (int r = 0; r < 4; ++r) {
        const int row = i * 16 + quad * 4 + r;
        O[((size_t)b * kHW + q0 + row) * kCV + wid * 32 + j * 16 + m] =
            __float2bfloat16(oc[i][j][r] * rowstat[row]);
      }
}

// ---- out = x + gamma * (O @ w_o), tile 128x128, dbuf, swizzled ----
__global__ __launch_bounds__(256) void k_out(const __hip_bfloat16* __restrict__ A,
                                             const __hip_bfloat16* __restrict__ Bw,
                                             const float* __restrict__ x,
                                             const float* __restrict__ gamma,
                                             float* __restrict__ out) {
  __shared__ __align__(16) char smem[4 * 16384];  // As[2] then Bs[2]
  const int tid = threadIdx.x, wid = tid >> 6, lane = tid & 63;
  const int m = lane & 15, quad = lane >> 4;
  const int row0 = blockIdx.x * 128, col0 = blockIdx.y * 128;
  const int wm = (wid >> 1) * 64, wn = (wid & 1) * 64;
  float4v acc[4][4] = {};
  auto stage = [&](int t, int buf) {
    const int kc = t * 64;
#pragma unroll
    for (int u = 0; u < 4; ++u) {
      const int r0 = (wid * 4 + u) * 8;
      const int row = r0 + (lane >> 3);
      const int og = (lane & 7) ^ (row & 7);
      gll16(A + (size_t)(row0 + row) * 256 + kc + og * 8, smem + buf * 16384 + r0 * 128);
      gll16(Bw + (size_t)(col0 + row) * 256 + kc + og * 8,
            smem + 32768 + buf * 16384 + r0 * 128);
    }
  };
  stage(0, 0);
  __syncthreads();
#pragma unroll
  for (int t = 0; t < 4; ++t) {
    if (t < 3) stage(t + 1, (t + 1) & 1);
    const char* Ab = smem + (t & 1) * 16384;
    const char* Bb = smem + 32768 + (t & 1) * 16384;
#pragma unroll
    for (int kk = 0; kk < 64; kk += 32) {
      const int oct = (kk >> 3) + quad;
      short8 af[4], bf[4];
#pragma unroll
      for (int i = 0; i < 4; ++i) af[i] = *fragp(Ab, wm + i * 16 + m, oct);
#pragma unroll
      for (int j = 0; j < 4; ++j) bf[j] = *fragp(Bb, wn + j * 16 + m, oct);
#pragma unroll
      for (int i = 0; i < 4; ++i)
#pragma unroll
        for (int j = 0; j < 4; ++j) acc[i][j] = mfma16(af[i], bf[j], acc[i][j]);
    }
    __syncthreads();
  }
  const float g = gamma[0];
#pragma unroll
  for (int i = 0; i < 4; ++i)
#pragma unroll
    for (int j = 0; j < 4; ++j) {
      const int cc = col0 + wn + j * 16 + m;
      const int rb = row0 + wm + i * 16 + quad * 4;
#pragma unroll
      for (int r = 0; r < 4; ++r) {
        const size_t idx = (size_t)(rb + r) * 512 + cc;
        out[idx] = x[idx] + g * acc[i][j][r];
      }
    }
}

extern "C" void kernel_launch(void* const* d_in, const int* in_sizes, int n_in,
                              void* d_out, int out_size, void* d_ws, size_t ws_size,
                              hipStream_t stream) {
  (void)in_sizes; (void)n_in; (void)out_size; (void)ws_size;
  const float* x     = (const float*)d_in[0];
  const float* wt    = (const float*)d_in[1];
  const float* wphi  = (const float*)d_in[2];
  const float* wg    = (const float*)d_in[3];
  const float* wo    = (const float*)d_in[4];
  const float* gamma = (const float*)d_in[5];
  float* out = (float*)d_out;

  char* ws = (char*)d_ws;
  __hip_bfloat16* wAll = (__hip_bfloat16*)(ws);              //    393,216
  __hip_bfloat16* woT  = (__hip_bfloat16*)(ws + 393216);     //    262,144
  __hip_bfloat16* pgf  = (__hip_bfloat16*)(ws + 655360);     // 25,165,824
  __hip_bfloat16* phip = (__hip_bfloat16*)(ws + 25821184);   //  1,048,576
  __hip_bfloat16* gT   = (__hip_bfloat16*)(ws + 26869760);   //  4,194,304
  __hip_bfloat16* O    = (__hip_bfloat16*)(ws + 31064064);   // 16,777,216  (total 47.8MB)

  k_pack_w<<<1280, 256, 0, stream>>>(wt, wphi, wg, wo, wAll, woT);
  k_proj<<<512, 256, 0, stream>>>(x, wAll, pgf);
  k_pool_phi<<<2048, 256, 0, stream>>>(pgf, phip);
  k_pool_gT<<<dim3(16, 4, 8), 256, 0, stream>>>(pgf, gT);
  k_fattn<<<dim3(kHW / 32, kB), 512, 0, stream>>>(pgf, phip, gT, O);
  k_out<<<dim3(256, 4), 256, 0, stream>>>(O, woT, x, gamma, out);
}